// Round 15
// baseline (57.278 us; speedup 1.0000x reference)
//
#include <hip/hip_runtime.h>

// MHAGRU, 2 kernels: [inproj + GRU + MHA fused, h LDS-resident] -> [out_proj].
// B=32 T=64 F=128 H=8 NH=4 HD=2 HID=32. f32 compute; bf16 ws intermediate.
// d_out = [ y (B*T*HID) | attention (B*T*F*H) ]
// d_ws  = [ out_bf16 (B*F,T,H) ushort ] (written by K1, read only by K2)
//
// R15: R14 (best known, 52.7us) + phase B spread over all 4 waves (wave w
// scans features {2w,2w+1} on lanes 0-15). Previously the scan ran on wave 0
// only -> SIMDs 1-3 idle ~3.2us per block (intra-block structural idle that
// occupancy can't fix, cf. R11 null). Everything else byte-identical to R14.

namespace {
constexpr int Bb = 32, Tt = 64, Ff = 128, Hh = 8, HIDh = 32;
constexpr int G3H = 24;
constexpr float L2E = 1.44269504088896340736f;
// K1 LDS (floats), phased overlays (R9/R14):
//  phase A: xs [0,8320) stride 130; xp [8320,8840)
//  phase B: hout [0,4160) (overlays xs); xp read
//  phase C: hout; OCT [4160,9280); WKV [9280,16192) 1728/wave
constexpr int XS_STRIDE = 130;
constexpr int XP = 8320;
constexpr int OCT = 4160;                 // o8 staging [8 f][64 t][10]
constexpr int WKV = 9280;                 // per-wave kv/q region
constexpr int KK0 = 0, KK1 = 272, VV0 = 544, VV1 = 816, QS = 1088;  // within WKV
constexpr int SM_SIZE = 16192;            // 64.8 KB -> 2 blocks/CU
}

__device__ __forceinline__ float rcp_(float x) {
#if __has_builtin(__builtin_amdgcn_rcpf)
  return __builtin_amdgcn_rcpf(x);
#else
  return 1.0f / x;
#endif
}
__device__ __forceinline__ float exp2_(float x) {
#if __has_builtin(__builtin_amdgcn_exp2f)
  return __builtin_amdgcn_exp2f(x);
#else
  return exp2f(x);
#endif
}
// f32 -> bf16 (round-to-nearest-even), packed pair -> one dword
__device__ __forceinline__ unsigned bfp_(float a, float b) {
  union { float f; unsigned u; } ca{a}, cb{b};
  unsigned ra = (ca.u + 0x7fffu + ((ca.u >> 16) & 1u)) >> 16;
  unsigned rb = (cb.u + 0x7fffu + ((cb.u >> 16) & 1u)) >> 16;
  return ra | (rb << 16);
}
__device__ __forceinline__ float bflo_(unsigned u) { return __uint_as_float(u << 16); }
__device__ __forceinline__ float bfhi_(unsigned u) { return __uint_as_float(u & 0xffff0000u); }

// 4-row softmax+PV step per kv component (R6/R8/R9 proven)
#define MHA_STEP(K0C, K1C, V0C, V1C)                         \
  {                                                          \
    _Pragma("unroll") for (int i = 0; i < 4; ++i) {          \
      float s = fmaf(q0[i], K0C, q1[i] * K1C);               \
      float p = exp2_(s);                                    \
      ps[i] += p;                                            \
      c0[i] = fmaf(p, V0C, c0[i]);                           \
      c1[i] = fmaf(p, V1C, c1[i]);                           \
    }                                                        \
  }

// ---------------- K1: input_proj + GRU + MHA, one block per (b, 8f) ----------------
// grid: B*(F/8) = 512 blocks, 256 threads = 4 waves.
__global__ __launch_bounds__(256, 2) void k_fused(
    const float* __restrict__ x, const float* __restrict__ Wp, const float* __restrict__ bp,
    const float* __restrict__ W_ih, const float* __restrict__ b_ih,
    const float* __restrict__ W_hh, const float* __restrict__ b_hh,
    const float* __restrict__ in_w, const float* __restrict__ in_b,
    const float* __restrict__ ow, const float* __restrict__ ob,
    ushort* __restrict__ outp, float* __restrict__ attn) {
  __shared__ float smem[SM_SIZE];
  const int tid = threadIdx.x;
  const int blk = blockIdx.x;
  const int b = blk >> 4;
  const int f0 = (blk & 15) * 8;
  const int lane = tid & 63;
  const int w = tid >> 6;

  // ---- phase A: stage x[b] (64x128); compute xp for this block's 8 f's ----
  {
    const float2* xb = (const float2*)(x + b * Tt * Ff);
    for (int i = tid; i < Tt * Ff / 2; i += 256) {
      int row = i >> 6, col2 = i & 63;
      *(float2*)&smem[row * XS_STRIDE + col2 * 2] = xb[i];
    }
  }
  __syncthreads();
  {
    const int t = lane;
    const int fA = f0 + w, fB = f0 + w + 4;  // wave-uniform -> scalar Wp loads
    float acc0 = bp[fA], acc1 = bp[fB];
    const float* wA = Wp + fA * Ff;
    const float* wB = Wp + fB * Ff;
    const float* xr = &smem[t * XS_STRIDE];
#pragma unroll 8
    for (int k = 0; k < Ff; k += 2) {
      float2 xv = *(const float2*)&xr[k];
      acc0 = fmaf(xv.x, wA[k], acc0); acc0 = fmaf(xv.y, wA[k + 1], acc0);
      acc1 = fmaf(xv.x, wB[k], acc1); acc1 = fmaf(xv.y, wB[k + 1], acc1);
    }
    smem[XP + w * 65 + t] = acc0;
    smem[XP + (w + 4) * 65 + t] = acc1;
  }
  __syncthreads();   // xp ready; xs region dead -> hout overlays it

  // ---- phase B: GRU scan over T; wave w scans features {2w, 2w+1} (lanes 0..15) ----
  if (lane < 16) {
    const int g = 2 * w + (lane >> 3);   // f_local 0..7 spread across waves
    const int j = lane & 7;
    const int f = f0 + g;
    const float* wb = W_hh + (f * G3H + j) * Hh;
    const float nL = -L2E, S2 = 2.0f * L2E;
    float w0s[8], w1s[8], w2s[8];
#pragma unroll
    for (int h = 0; h < 8; ++h) {
      w0s[h] = wb[h] * nL;
      w1s[h] = wb[64 + h] * nL;
      w2s[h] = wb[128 + h] * S2;
    }
    const float wi0s = W_ih[f * G3H + j] * nL;
    const float wi1s = W_ih[f * G3H + 8 + j] * nL;
    const float wi2s = W_ih[f * G3H + 16 + j] * S2;
    const float bias_r = (b_ih[f * G3H + j] + b_hh[f * G3H + j]) * nL;
    const float bias_z = (b_ih[f * G3H + 8 + j] + b_hh[f * G3H + 8 + j]) * nL;
    const float bi2s = b_ih[f * G3H + 16 + j] * S2;
    const float bh2s = b_hh[f * G3H + 16 + j] * S2;
    float hall[8];
#pragma unroll
    for (int h = 0; h < 8; ++h) hall[h] = 0.f;
    float h_own = 0.f;                    // == hall[j] without dynamic index
    const int base = lane & 56;           // 0 or 8: 8-lane shuffle group intact
    float* hdst = &smem[g * 520 + j * 65];   // hout[g][j][t]
    const float* xps = &smem[XP + g * 65];
    for (int t = 0; t < Tt; ++t) {
      float xt = xps[t];
      float a0 = bias_r, a1 = bias_z, a2 = bh2s;
#pragma unroll
      for (int h = 0; h < 8; ++h) {
        a0 = fmaf(hall[h], w0s[h], a0);
        a1 = fmaf(hall[h], w1s[h], a1);
        a2 = fmaf(hall[h], w2s[h], a2);
      }
      float r = rcp_(1.0f + exp2_(fmaf(xt, wi0s, a0)));
      float z = rcp_(1.0f + exp2_(fmaf(xt, wi1s, a1)));
      float narg = fmaf(r, a2, fmaf(xt, wi2s, bi2s));
      float n = fmaf(-2.0f, rcp_(exp2_(narg) + 1.0f), 1.0f);  // tanh
      float hn = fmaf(z, h_own - n, n);
      hdst[t] = hn;
      h_own = hn;
#pragma unroll
      for (int h = 0; h < 8; ++h) hall[h] = __shfl(hn, base + h, 64);
    }
  }
  __syncthreads();   // hout ready for all waves

  // ---- burst-write h tile to global as bf16: 8f x 64t rows of 8 bf16 (16B each) ----
  {
    ushort* og = outp + (size_t)(b * Ff + f0) * Tt * Hh;
#pragma unroll
    for (int i = 0; i < 2; ++i) {
      int v = i * 256 + tid;               // row index (512 total)
      int fl = v >> 6, tt = v & 63;
      const float* hp = &smem[fl * 520 + tt];
      unsigned d0 = bfp_(hp[0],   hp[65]);
      unsigned d1 = bfp_(hp[130], hp[195]);
      unsigned d2 = bfp_(hp[260], hp[325]);
      unsigned d3 = bfp_(hp[390], hp[455]);
      *(uint4*)(og + (size_t)v * 8) = make_uint4(d0, d1, d2, d3);
    }
  }

  // ---- phase C: MHA; wave w handles f_local = w and w+4, fully wave-private ----
  {
    const int t = lane;
    float* sm = &smem[WKV + w * 1728];
    constexpr float SCL = 0.70710678118654752f * L2E;
#pragma unroll
    for (int fl = w; fl < 8; fl += 4) {
      const float* hsrc = &smem[fl * 520];
      // C1: qkv projection from LDS-resident f32 h
      float sq[8];
#pragma unroll
      for (int h = 0; h < 8; ++h) sq[h] = hsrc[h * 65 + t];
      float qv[8], ka[8], va[8];
#pragma unroll
      for (int jj = 0; jj < 8; ++jj) {
        float aq = in_b[jj], ak = in_b[8 + jj], av = in_b[16 + jj];
#pragma unroll
        for (int h = 0; h < 8; ++h) {
          aq = fmaf(sq[h], in_w[jj * 8 + h], aq);
          ak = fmaf(sq[h], in_w[(8 + jj) * 8 + h], ak);
          av = fmaf(sq[h], in_w[(16 + jj) * 8 + h], av);
        }
        qv[jj] = aq * SCL; ka[jj] = ak; va[jj] = av;
      }
#pragma unroll
      for (int n = 0; n < 4; ++n) {
        *(float2*)&sm[QS + t * 10 + 2 * n] = make_float2(qv[2 * n], qv[2 * n + 1]);
        sm[KK0 + n * 68 + t] = ka[2 * n];
        sm[KK1 + n * 68 + t] = ka[2 * n + 1];
        sm[VV0 + n * 68 + t] = va[2 * n];
        sm[VV1 + n * 68 + t] = va[2 * n + 1];
      }
      asm volatile("s_waitcnt lgkmcnt(0)" ::: "memory");  // within-wave RAW

      // C2: lane = (n = t>>4, qq = t&15); 4 q-rows x 1 head
      const int n = t >> 4, qq = t & 15;
      float q0[4], q1[4];
#pragma unroll
      for (int i = 0; i < 4; ++i) {
        float2 qp = *(const float2*)&sm[QS + (qq + 16 * i) * 10 + 2 * n];
        q0[i] = qp.x; q1[i] = qp.y;
      }
      float ps[4], c0[4], c1[4];
#pragma unroll
      for (int i = 0; i < 4; ++i) { ps[i] = 0.f; c0[i] = 0.f; c1[i] = 0.f; }
#pragma unroll 2
      for (int kt4 = 0; kt4 < Tt; kt4 += 4) {
        float4 k0 = *(const float4*)&sm[KK0 + n * 68 + kt4];
        float4 k1 = *(const float4*)&sm[KK1 + n * 68 + kt4];
        float4 v0 = *(const float4*)&sm[VV0 + n * 68 + kt4];
        float4 v1 = *(const float4*)&sm[VV1 + n * 68 + kt4];
        MHA_STEP(k0.x, k1.x, v0.x, v1.x)
        MHA_STEP(k0.y, k1.y, v0.y, v1.y)
        MHA_STEP(k0.z, k1.z, v0.z, v1.z)
        MHA_STEP(k0.w, k1.w, v0.w, v1.w)
      }
#pragma unroll
      for (int i = 0; i < 4; ++i) {
        float inv = rcp_(ps[i]);
        *(float2*)&sm[QS + (qq + 16 * i) * 10 + 2 * n] =
            make_float2(c0[i] * inv, c1[i] * inv);   // ctx over q
      }
      asm volatile("s_waitcnt lgkmcnt(0)" ::: "memory");

      // C3: out_proj of ctx row t -> stage in OCT
      {
        float2 cp0 = *(const float2*)&sm[QS + t * 10 + 0];
        float2 cp1 = *(const float2*)&sm[QS + t * 10 + 2];
        float2 cp2 = *(const float2*)&sm[QS + t * 10 + 4];
        float2 cp3 = *(const float2*)&sm[QS + t * 10 + 6];
        float cx[8] = {cp0.x, cp0.y, cp1.x, cp1.y, cp2.x, cp2.y, cp3.x, cp3.y};
        float o8[8];
#pragma unroll
        for (int jj = 0; jj < 8; ++jj) {
          float a = ob[jj];
#pragma unroll
          for (int h = 0; h < 8; ++h) a = fmaf(cx[h], ow[jj * 8 + h], a);
          o8[jj] = a;
        }
        float* od = &smem[OCT + fl * 640 + t * 10];
        *(float4*)&od[0] = make_float4(o8[0], o8[1], o8[2], o8[3]);
        *(float4*)&od[4] = make_float4(o8[4], o8[5], o8[6], o8[7]);
      }
    }
  }
  __syncthreads();

  // ---- burst attn store: per t, 8f x 8h = 256B contiguous ----
  {
#pragma unroll
    for (int i = 0; i < 4; ++i) {
      int v = i * 256 + tid;            // float4 index (1024 total)
      int t = v >> 4;
      int c = v & 15;                   // f = c>>1, h0 = (c&1)*4
      const float* sp = &smem[OCT + (c >> 1) * 640 + t * 10 + (c & 1) * 4];
      float4* dst = (float4*)(attn + ((b * Tt + t) * Ff + f0) * Hh);
      dst[c] = *(const float4*)sp;
    }
  }
}

// ---------------- K2: y = out.reshape(B,T,F*H) @ Wout^T + bout (bf16 reads) ----------------
// grid: B*(T/8) = 256 blocks, 128 threads = 8 o-quads x 16 f-chunks (R2 proven shape).
__global__ __launch_bounds__(128) void k_outproj(
    const ushort* __restrict__ outp, const float* __restrict__ Wout,
    const float* __restrict__ bout, float* __restrict__ y) {
  constexpr int TT = 8;
  int blk = blockIdx.x;
  int b = blk >> 3;
  int t0 = (blk & 7) * TT;
  int tid = threadIdx.x;
  int oq = tid >> 4;
  int fc = tid & 15;
  float acc[TT][4];
#pragma unroll
  for (int tt = 0; tt < TT; ++tt)
#pragma unroll
    for (int od = 0; od < 4; ++od) acc[tt][od] = 0.f;
#pragma unroll
  for (int ff = 0; ff < 8; ++ff) {
    int f = fc * 8 + ff;
    const uint4* rb = (const uint4*)(outp + (size_t)((b * Ff + f) * Tt + t0) * Hh);
    uint4 rq[TT];
#pragma unroll
    for (int i = 0; i < TT; ++i) rq[i] = rb[i];   // one uint4 = one t row (8 bf16)
    float4 rv[16];
#pragma unroll
    for (int tt = 0; tt < TT; ++tt) {
      uint4 q = rq[tt];
      rv[tt * 2]     = make_float4(bflo_(q.x), bfhi_(q.x), bflo_(q.y), bfhi_(q.y));
      rv[tt * 2 + 1] = make_float4(bflo_(q.z), bfhi_(q.z), bflo_(q.w), bfhi_(q.w));
    }
#pragma unroll
    for (int od = 0; od < 4; ++od) {
      int o = oq * 4 + od;
      const float4* wbp = (const float4*)(Wout + o * (Ff * Hh) + f * Hh);
      float4 wa = wbp[0], wc = wbp[1];
#pragma unroll
      for (int tt = 0; tt < TT; ++tt) {
        float4 ra = rv[tt * 2], rc = rv[tt * 2 + 1];
        float s = acc[tt][od];
        s = fmaf(ra.x, wa.x, s); s = fmaf(ra.y, wa.y, s);
        s = fmaf(ra.z, wa.z, s); s = fmaf(ra.w, wa.w, s);
        s = fmaf(rc.x, wc.x, s); s = fmaf(rc.y, wc.y, s);
        s = fmaf(rc.z, wc.z, s); s = fmaf(rc.w, wc.w, s);
        acc[tt][od] = s;
      }
    }
  }
#pragma unroll
  for (int tt = 0; tt < TT; ++tt)
#pragma unroll
    for (int od = 0; od < 4; ++od) {
      float v = acc[tt][od];
      v += __shfl_xor(v, 1, 16);
      v += __shfl_xor(v, 2, 16);
      v += __shfl_xor(v, 4, 16);
      v += __shfl_xor(v, 8, 16);
      acc[tt][od] = v;
    }
#pragma unroll
  for (int tt = 0; tt < TT; ++tt) {
    if (fc == tt) {
#pragma unroll
      for (int od = 0; od < 4; ++od) {
        int o = oq * 4 + od;
        y[(b * Tt + t0 + tt) * HIDh + o] = acc[tt][od] + bout[o];
      }
    }
  }
}

extern "C" void kernel_launch(void* const* d_in, const int* in_sizes, int n_in,
                              void* d_out, int out_size, void* d_ws, size_t ws_size,
                              hipStream_t stream) {
  (void)in_sizes; (void)n_in; (void)out_size; (void)ws_size;
  const float* x    = (const float*)d_in[0];
  const float* Wp   = (const float*)d_in[1];
  const float* bp   = (const float*)d_in[2];
  const float* W_ih = (const float*)d_in[3];
  const float* b_ih = (const float*)d_in[4];
  const float* W_hh = (const float*)d_in[5];
  const float* b_hh = (const float*)d_in[6];
  const float* in_w = (const float*)d_in[7];
  const float* in_b = (const float*)d_in[8];
  const float* ow   = (const float*)d_in[9];
  const float* ob   = (const float*)d_in[10];
  const float* Wout = (const float*)d_in[11];
  const float* bout = (const float*)d_in[12];

  float* y     = (float*)d_out;
  float* attn  = (float*)d_out + Bb * Tt * HIDh;
  ushort* outp = (ushort*)d_ws;   // B*F*T*H bf16 (4 MB)

  hipLaunchKernelGGL(k_fused, dim3(Bb * (Ff / 8)), dim3(256), 0, stream,
                     x, Wp, bp, W_ih, b_ih, W_hh, b_hh, in_w, in_b, ow, ob, outp, attn);
  hipLaunchKernelGGL(k_outproj, dim3(Bb * (Tt / 8)), dim3(128), 0, stream,
                     outp, Wout, bout, y);
}

// Round 16
// 55.389 us; speedup vs baseline: 1.0341x; 1.0341x over previous
//
#include <hip/hip_runtime.h>

// MHAGRU, 2 kernels: [inproj + GRU + MHA fused, h LDS-resident] -> [out_proj].
// B=32 T=64 F=128 H=8 NH=4 HD=2 HID=32. f32 compute; bf16 ws intermediate.
// d_out = [ y (B*T*HID) | attention (B*T*F*H) ]
// d_ws  = [ out_bf16 (B*F,T,H) ushort ] (written by K1, read only by K2)
//
// R16: R14 (best, 52.7us; B on wave 0 only -- R15's spread-B regressed) with
// phase C restructured: both of a wave's features (w, w+4) interleaved in ONE
// C2 loop -- 8 ds_read_b128 + 2x independent compute per kt4 (24 acc chains).
// Halves latency-exposed iterations; q/ctx lives in the OCT row buffer,
// freeing per-wave LDS for the second kv set (71.9KB, still 2 blocks/CU).

namespace {
constexpr int Bb = 32, Tt = 64, Ff = 128, Hh = 8, HIDh = 32;
constexpr int G3H = 24;
constexpr float L2E = 1.44269504088896340736f;
// K1 LDS (floats), phased overlays:
//  phase A: xs [0,8320) stride 130; xp [8320,8840)
//  phase B: hout [0,4160) (overlays xs); xp read
//  phase C: hout [0,4160); OCT [4160,9280) q/ctx/o8 [8f][64t][10];
//           WKV [9280,17984) = per-wave kvA(1088)+kvB(1088)
constexpr int XS_STRIDE = 130;
constexpr int XP = 8320;
constexpr int OCT = 4160;
constexpr int WKV = 9280;
constexpr int SM_SIZE = WKV + 4 * 2176;   // 17984 floats = 71.9 KB -> 2 blocks/CU
}

__device__ __forceinline__ float rcp_(float x) {
#if __has_builtin(__builtin_amdgcn_rcpf)
  return __builtin_amdgcn_rcpf(x);
#else
  return 1.0f / x;
#endif
}
__device__ __forceinline__ float exp2_(float x) {
#if __has_builtin(__builtin_amdgcn_exp2f)
  return __builtin_amdgcn_exp2f(x);
#else
  return exp2f(x);
#endif
}
// f32 -> bf16 (round-to-nearest-even), packed pair -> one dword
__device__ __forceinline__ unsigned bfp_(float a, float b) {
  union { float f; unsigned u; } ca{a}, cb{b};
  unsigned ra = (ca.u + 0x7fffu + ((ca.u >> 16) & 1u)) >> 16;
  unsigned rb = (cb.u + 0x7fffu + ((cb.u >> 16) & 1u)) >> 16;
  return ra | (rb << 16);
}
__device__ __forceinline__ float bflo_(unsigned u) { return __uint_as_float(u << 16); }
__device__ __forceinline__ float bfhi_(unsigned u) { return __uint_as_float(u & 0xffff0000u); }

// 4-row softmax+PV step, parameterized accumulator set (A or B feature)
#define MHA_STEP2(Q0, Q1, PS, C0, C1, K0C, K1C, V0C, V1C)    \
  {                                                          \
    _Pragma("unroll") for (int i = 0; i < 4; ++i) {          \
      float s = fmaf(Q0[i], K0C, Q1[i] * K1C);               \
      float p = exp2_(s);                                    \
      PS[i] += p;                                            \
      C0[i] = fmaf(p, V0C, C0[i]);                           \
      C1[i] = fmaf(p, V1C, C1[i]);                           \
    }                                                        \
  }

// ---------------- K1: input_proj + GRU + MHA, one block per (b, 8f) ----------------
// grid: B*(F/8) = 512 blocks, 256 threads = 4 waves.
__global__ __launch_bounds__(256, 2) void k_fused(
    const float* __restrict__ x, const float* __restrict__ Wp, const float* __restrict__ bp,
    const float* __restrict__ W_ih, const float* __restrict__ b_ih,
    const float* __restrict__ W_hh, const float* __restrict__ b_hh,
    const float* __restrict__ in_w, const float* __restrict__ in_b,
    const float* __restrict__ ow, const float* __restrict__ ob,
    ushort* __restrict__ outp, float* __restrict__ attn) {
  __shared__ float smem[SM_SIZE];
  const int tid = threadIdx.x;
  const int blk = blockIdx.x;
  const int b = blk >> 4;
  const int f0 = (blk & 15) * 8;
  const int lane = tid & 63;
  const int w = tid >> 6;

  // ---- phase A: stage x[b] (64x128); compute xp for this block's 8 f's ----
  {
    const float2* xb = (const float2*)(x + b * Tt * Ff);
    for (int i = tid; i < Tt * Ff / 2; i += 256) {
      int row = i >> 6, col2 = i & 63;
      *(float2*)&smem[row * XS_STRIDE + col2 * 2] = xb[i];
    }
  }
  __syncthreads();
  {
    const int t = lane;
    const int fA = f0 + w, fB = f0 + w + 4;  // wave-uniform -> scalar Wp loads
    float acc0 = bp[fA], acc1 = bp[fB];
    const float* wA = Wp + fA * Ff;
    const float* wB = Wp + fB * Ff;
    const float* xr = &smem[t * XS_STRIDE];
#pragma unroll 8
    for (int k = 0; k < Ff; k += 2) {
      float2 xv = *(const float2*)&xr[k];
      acc0 = fmaf(xv.x, wA[k], acc0); acc0 = fmaf(xv.y, wA[k + 1], acc0);
      acc1 = fmaf(xv.x, wB[k], acc1); acc1 = fmaf(xv.y, wB[k + 1], acc1);
    }
    smem[XP + w * 65 + t] = acc0;
    smem[XP + (w + 4) * 65 + t] = acc1;
  }
  __syncthreads();   // xp ready; xs region dead -> hout overlays it

  // ---- phase B: GRU scan over T, wave 0 only (R14 proven); h -> LDS ----
  if (tid < 64) {
    __builtin_amdgcn_s_setprio(1);
    const int g = tid >> 3, j = tid & 7;
    const int f = f0 + g;
    const float* wb = W_hh + (f * G3H + j) * Hh;
    const float nL = -L2E, S2 = 2.0f * L2E;
    float w0s[8], w1s[8], w2s[8];
#pragma unroll
    for (int h = 0; h < 8; ++h) {
      w0s[h] = wb[h] * nL;
      w1s[h] = wb[64 + h] * nL;
      w2s[h] = wb[128 + h] * S2;
    }
    const float wi0s = W_ih[f * G3H + j] * nL;
    const float wi1s = W_ih[f * G3H + 8 + j] * nL;
    const float wi2s = W_ih[f * G3H + 16 + j] * S2;
    const float bias_r = (b_ih[f * G3H + j] + b_hh[f * G3H + j]) * nL;
    const float bias_z = (b_ih[f * G3H + 8 + j] + b_hh[f * G3H + 8 + j]) * nL;
    const float bi2s = b_ih[f * G3H + 16 + j] * S2;
    const float bh2s = b_hh[f * G3H + 16 + j] * S2;
    float hall[8];
#pragma unroll
    for (int h = 0; h < 8; ++h) hall[h] = 0.f;
    float h_own = 0.f;
    const int base = tid & 56;
    float* hdst = &smem[g * 520 + j * 65];   // hout[g][j][t]
    const float* xps = &smem[XP + g * 65];
    for (int t = 0; t < Tt; ++t) {
      float xt = xps[t];
      float a0 = bias_r, a1 = bias_z, a2 = bh2s;
#pragma unroll
      for (int h = 0; h < 8; ++h) {
        a0 = fmaf(hall[h], w0s[h], a0);
        a1 = fmaf(hall[h], w1s[h], a1);
        a2 = fmaf(hall[h], w2s[h], a2);
      }
      float r = rcp_(1.0f + exp2_(fmaf(xt, wi0s, a0)));
      float z = rcp_(1.0f + exp2_(fmaf(xt, wi1s, a1)));
      float narg = fmaf(r, a2, fmaf(xt, wi2s, bi2s));
      float n = fmaf(-2.0f, rcp_(exp2_(narg) + 1.0f), 1.0f);  // tanh
      float hn = fmaf(z, h_own - n, n);
      hdst[t] = hn;
      h_own = hn;
#pragma unroll
      for (int h = 0; h < 8; ++h) hall[h] = __shfl(hn, base + h, 64);
    }
    __builtin_amdgcn_s_setprio(0);
  }
  __syncthreads();   // hout ready for all waves

  // ---- burst-write h tile to global as bf16: 8f x 64t rows of 8 bf16 (16B each) ----
  {
    ushort* og = outp + (size_t)(b * Ff + f0) * Tt * Hh;
#pragma unroll
    for (int i = 0; i < 2; ++i) {
      int v = i * 256 + tid;               // row index (512 total)
      int fl = v >> 6, tt = v & 63;
      const float* hp = &smem[fl * 520 + tt];
      unsigned d0 = bfp_(hp[0],   hp[65]);
      unsigned d1 = bfp_(hp[130], hp[195]);
      unsigned d2 = bfp_(hp[260], hp[325]);
      unsigned d3 = bfp_(hp[390], hp[455]);
      *(uint4*)(og + (size_t)v * 8) = make_uint4(d0, d1, d2, d3);
    }
  }

  // ---- phase C: MHA; wave w owns features w and w+4, INTERLEAVED in one C2 ----
  {
    const int t = lane;
    float* kvA = &smem[WKV + w * 2176];
    float* kvB = kvA + 1088;
    constexpr float SCL = 0.70710678118654752f * L2E;

    // C1 for both features: q -> OCT row buffer; kv -> component-split arrays
#pragma unroll
    for (int half = 0; half < 2; ++half) {
      const int fl = w + 4 * half;
      const float* hsrc = &smem[fl * 520];
      float* kv = half ? kvB : kvA;
      float* oc = &smem[OCT + fl * 640];
      float sq[8];
#pragma unroll
      for (int h = 0; h < 8; ++h) sq[h] = hsrc[h * 65 + t];   // conflict-free
      float qv[8], ka[8], va[8];
#pragma unroll
      for (int jj = 0; jj < 8; ++jj) {
        float aq = in_b[jj], ak = in_b[8 + jj], av = in_b[16 + jj];
#pragma unroll
        for (int h = 0; h < 8; ++h) {
          aq = fmaf(sq[h], in_w[jj * 8 + h], aq);
          ak = fmaf(sq[h], in_w[(8 + jj) * 8 + h], ak);
          av = fmaf(sq[h], in_w[(16 + jj) * 8 + h], av);
        }
        qv[jj] = aq * SCL; ka[jj] = ak; va[jj] = av;
      }
#pragma unroll
      for (int n = 0; n < 4; ++n) {
        *(float2*)&oc[t * 10 + 2 * n] = make_float2(qv[2 * n], qv[2 * n + 1]);
        kv[0   + n * 68 + t] = ka[2 * n];
        kv[272 + n * 68 + t] = ka[2 * n + 1];
        kv[544 + n * 68 + t] = va[2 * n];
        kv[816 + n * 68 + t] = va[2 * n + 1];
      }
    }
    asm volatile("s_waitcnt lgkmcnt(0)" ::: "memory");   // within-wave RAW

    // C2: lane = (n = t>>4, qq = t&15); 4 q-rows x 1 head x BOTH features
    const int n = t >> 4, qq = t & 15;
    float* ocA = &smem[OCT + w * 640];
    float* ocB = &smem[OCT + (w + 4) * 640];
    float q0A[4], q1A[4], q0B[4], q1B[4];
#pragma unroll
    for (int i = 0; i < 4; ++i) {
      float2 qa = *(const float2*)&ocA[(qq + 16 * i) * 10 + 2 * n];
      float2 qb = *(const float2*)&ocB[(qq + 16 * i) * 10 + 2 * n];
      q0A[i] = qa.x; q1A[i] = qa.y;
      q0B[i] = qb.x; q1B[i] = qb.y;
    }
    float psA[4], c0A[4], c1A[4], psB[4], c0B[4], c1B[4];
#pragma unroll
    for (int i = 0; i < 4; ++i) {
      psA[i] = 0.f; c0A[i] = 0.f; c1A[i] = 0.f;
      psB[i] = 0.f; c0B[i] = 0.f; c1B[i] = 0.f;
    }
    for (int kt4 = 0; kt4 < Tt; kt4 += 4) {
      float4 k0a = *(const float4*)&kvA[0   + n * 68 + kt4];
      float4 k1a = *(const float4*)&kvA[272 + n * 68 + kt4];
      float4 v0a = *(const float4*)&kvA[544 + n * 68 + kt4];
      float4 v1a = *(const float4*)&kvA[816 + n * 68 + kt4];
      float4 k0b = *(const float4*)&kvB[0   + n * 68 + kt4];
      float4 k1b = *(const float4*)&kvB[272 + n * 68 + kt4];
      float4 v0b = *(const float4*)&kvB[544 + n * 68 + kt4];
      float4 v1b = *(const float4*)&kvB[816 + n * 68 + kt4];
      MHA_STEP2(q0A, q1A, psA, c0A, c1A, k0a.x, k1a.x, v0a.x, v1a.x)
      MHA_STEP2(q0B, q1B, psB, c0B, c1B, k0b.x, k1b.x, v0b.x, v1b.x)
      MHA_STEP2(q0A, q1A, psA, c0A, c1A, k0a.y, k1a.y, v0a.y, v1a.y)
      MHA_STEP2(q0B, q1B, psB, c0B, c1B, k0b.y, k1b.y, v0b.y, v1b.y)
      MHA_STEP2(q0A, q1A, psA, c0A, c1A, k0a.z, k1a.z, v0a.z, v1a.z)
      MHA_STEP2(q0B, q1B, psB, c0B, c1B, k0b.z, k1b.z, v0b.z, v1b.z)
      MHA_STEP2(q0A, q1A, psA, c0A, c1A, k0a.w, k1a.w, v0a.w, v1a.w)
      MHA_STEP2(q0B, q1B, psB, c0B, c1B, k0b.w, k1b.w, v0b.w, v1b.w)
    }
#pragma unroll
    for (int i = 0; i < 4; ++i) {
      float invA = rcp_(psA[i]);
      float invB = rcp_(psB[i]);
      *(float2*)&ocA[(qq + 16 * i) * 10 + 2 * n] = make_float2(c0A[i] * invA, c1A[i] * invA);
      *(float2*)&ocB[(qq + 16 * i) * 10 + 2 * n] = make_float2(c0B[i] * invB, c1B[i] * invB);
    }
    asm volatile("s_waitcnt lgkmcnt(0)" ::: "memory");

    // C3 for both features: out_proj of ctx row t, o8 back into own row
#pragma unroll
    for (int half = 0; half < 2; ++half) {
      float* oc = &smem[OCT + (w + 4 * half) * 640];
      float2 cp0 = *(const float2*)&oc[t * 10 + 0];
      float2 cp1 = *(const float2*)&oc[t * 10 + 2];
      float2 cp2 = *(const float2*)&oc[t * 10 + 4];
      float2 cp3 = *(const float2*)&oc[t * 10 + 6];
      float cx[8] = {cp0.x, cp0.y, cp1.x, cp1.y, cp2.x, cp2.y, cp3.x, cp3.y};
      float o8[8];
#pragma unroll
      for (int jj = 0; jj < 8; ++jj) {
        float a = ob[jj];
#pragma unroll
        for (int h = 0; h < 8; ++h) a = fmaf(cx[h], ow[jj * 8 + h], a);
        o8[jj] = a;
      }
      *(float4*)&oc[t * 10 + 0] = make_float4(o8[0], o8[1], o8[2], o8[3]);
      *(float4*)&oc[t * 10 + 4] = make_float4(o8[4], o8[5], o8[6], o8[7]);
    }
  }
  __syncthreads();

  // ---- burst attn store: per t, 8f x 8h = 256B contiguous ----
  {
#pragma unroll
    for (int i = 0; i < 4; ++i) {
      int v = i * 256 + tid;            // float4 index (1024 total)
      int t = v >> 4;
      int c = v & 15;                   // f = c>>1, h0 = (c&1)*4
      const float* sp = &smem[OCT + (c >> 1) * 640 + t * 10 + (c & 1) * 4];
      float4* dst = (float4*)(attn + ((b * Tt + t) * Ff + f0) * Hh);
      dst[c] = *(const float4*)sp;
    }
  }
}

// ---------------- K2: y = out.reshape(B,T,F*H) @ Wout^T + bout (bf16 reads) ----------------
// grid: B*(T/8) = 256 blocks, 128 threads = 8 o-quads x 16 f-chunks.
__global__ __launch_bounds__(128) void k_outproj(
    const ushort* __restrict__ outp, const float* __restrict__ Wout,
    const float* __restrict__ bout, float* __restrict__ y) {
  constexpr int TT = 8;
  int blk = blockIdx.x;
  int b = blk >> 3;
  int t0 = (blk & 7) * TT;
  int tid = threadIdx.x;
  int oq = tid >> 4;
  int fc = tid & 15;
  float acc[TT][4];
#pragma unroll
  for (int tt = 0; tt < TT; ++tt)
#pragma unroll
    for (int od = 0; od < 4; ++od) acc[tt][od] = 0.f;
#pragma unroll
  for (int ff = 0; ff < 8; ++ff) {
    int f = fc * 8 + ff;
    const uint4* rb = (const uint4*)(outp + (size_t)((b * Ff + f) * Tt + t0) * Hh);
    uint4 rq[TT];
#pragma unroll
    for (int i = 0; i < TT; ++i) rq[i] = rb[i];   // one uint4 = one t row (8 bf16)
    float4 rv[16];
#pragma unroll
    for (int tt = 0; tt < TT; ++tt) {
      uint4 q = rq[tt];
      rv[tt * 2]     = make_float4(bflo_(q.x), bfhi_(q.x), bflo_(q.y), bfhi_(q.y));
      rv[tt * 2 + 1] = make_float4(bflo_(q.z), bfhi_(q.z), bflo_(q.w), bfhi_(q.w));
    }
#pragma unroll
    for (int od = 0; od < 4; ++od) {
      int o = oq * 4 + od;
      const float4* wbp = (const float4*)(Wout + o * (Ff * Hh) + f * Hh);
      float4 wa = wbp[0], wc = wbp[1];
#pragma unroll
      for (int tt = 0; tt < TT; ++tt) {
        float4 ra = rv[tt * 2], rc = rv[tt * 2 + 1];
        float s = acc[tt][od];
        s = fmaf(ra.x, wa.x, s); s = fmaf(ra.y, wa.y, s);
        s = fmaf(ra.z, wa.z, s); s = fmaf(ra.w, wa.w, s);
        s = fmaf(rc.x, wc.x, s); s = fmaf(rc.y, wc.y, s);
        s = fmaf(rc.z, wc.z, s); s = fmaf(rc.w, wc.w, s);
        acc[tt][od] = s;
      }
    }
  }
#pragma unroll
  for (int tt = 0; tt < TT; ++tt)
#pragma unroll
    for (int od = 0; od < 4; ++od) {
      float v = acc[tt][od];
      v += __shfl_xor(v, 1, 16);
      v += __shfl_xor(v, 2, 16);
      v += __shfl_xor(v, 4, 16);
      v += __shfl_xor(v, 8, 16);
      acc[tt][od] = v;
    }
#pragma unroll
  for (int tt = 0; tt < TT; ++tt) {
    if (fc == tt) {
#pragma unroll
      for (int od = 0; od < 4; ++od) {
        int o = oq * 4 + od;
        y[(b * Tt + t0 + tt) * HIDh + o] = acc[tt][od] + bout[o];
      }
    }
  }
}

extern "C" void kernel_launch(void* const* d_in, const int* in_sizes, int n_in,
                              void* d_out, int out_size, void* d_ws, size_t ws_size,
                              hipStream_t stream) {
  (void)in_sizes; (void)n_in; (void)out_size; (void)ws_size;
  const float* x    = (const float*)d_in[0];
  const float* Wp   = (const float*)d_in[1];
  const float* bp   = (const float*)d_in[2];
  const float* W_ih = (const float*)d_in[3];
  const float* b_ih = (const float*)d_in[4];
  const float* W_hh = (const float*)d_in[5];
  const float* b_hh = (const float*)d_in[6];
  const float* in_w = (const float*)d_in[7];
  const float* in_b = (const float*)d_in[8];
  const float* ow   = (const float*)d_in[9];
  const float* ob   = (const float*)d_in[10];
  const float* Wout = (const float*)d_in[11];
  const float* bout = (const float*)d_in[12];

  float* y     = (float*)d_out;
  float* attn  = (float*)d_out + Bb * Tt * HIDh;
  ushort* outp = (ushort*)d_ws;   // B*F*T*H bf16 (4 MB)

  hipLaunchKernelGGL(k_fused, dim3(Bb * (Ff / 8)), dim3(256), 0, stream,
                     x, Wp, bp, W_ih, b_ih, W_hh, b_hh, in_w, in_b, ow, ob, outp, attn);
  hipLaunchKernelGGL(k_outproj, dim3(Bb * (Tt / 8)), dim3(128), 0, stream,
                     outp, Wout, bout, y);
}

// Round 17
// 52.673 us; speedup vs baseline: 1.0874x; 1.0516x over previous
//
#include <hip/hip_runtime.h>

// MHAGRU FINAL (revert to R14, session best: 52.7us).
// 2 kernels: [inproj + GRU + MHA fused, h LDS-resident] -> [out_proj].
// B=32 T=64 F=128 H=8 NH=4 HD=2 HID=32. f32 compute; bf16 ws intermediate.
// d_out = [ y (B*T*HID) | attention (B*T*F*H) ]
// d_ws  = [ out_bf16 (B*F,T,H) ushort ] (written by K1, read only by K2)
//
// Session summary (75 -> 52.7us): fdiv->v_rcp/v_exp2 with log2e folded into
// GRU weights (-9us); fuse inproj+GRU+MHA with h LDS-resident (-8us); burst
// stores everywhere (stores were 4KB-stride 32B scatters -> DRAM thrash);
// bf16 intermediate for the out_proj operand (-4us). Falsified: occupancy x2
// (R11 null), wave-count x4 (R10 neg), barrier-free (R10 neg), B-spread (R15
// neg), C2 ILP x2 (R16 neg), y-atomics (R13: 9x write amplification).
// Remaining wall = issue(~16us) x ~2.6 latency-fog at 2 blocks/CU; no lever
// in the proven catalog moves it.

namespace {
constexpr int Bb = 32, Tt = 64, Ff = 128, Hh = 8, HIDh = 32;
constexpr int G3H = 24;
constexpr float L2E = 1.44269504088896340736f;
// K1 LDS (floats), phased overlays:
//  phase A: xs [0,8320) stride 130; xp [8320,8840)
//  phase B: hout [0,4160) (overlays xs); xp read
//  phase C: hout; OCT [4160,9280); WKV [9280,16192) 1728/wave
constexpr int XS_STRIDE = 130;
constexpr int XP = 8320;
constexpr int OCT = 4160;                 // o8 staging [8 f][64 t][10]
constexpr int WKV = 9280;                 // per-wave kv/q region
constexpr int KK0 = 0, KK1 = 272, VV0 = 544, VV1 = 816, QS = 1088;  // within WKV
constexpr int SM_SIZE = 16192;            // 64.8 KB -> 2 blocks/CU
}

__device__ __forceinline__ float rcp_(float x) {
#if __has_builtin(__builtin_amdgcn_rcpf)
  return __builtin_amdgcn_rcpf(x);
#else
  return 1.0f / x;
#endif
}
__device__ __forceinline__ float exp2_(float x) {
#if __has_builtin(__builtin_amdgcn_exp2f)
  return __builtin_amdgcn_exp2f(x);
#else
  return exp2f(x);
#endif
}
// f32 -> bf16 (round-to-nearest-even), packed pair -> one dword
__device__ __forceinline__ unsigned bfp_(float a, float b) {
  union { float f; unsigned u; } ca{a}, cb{b};
  unsigned ra = (ca.u + 0x7fffu + ((ca.u >> 16) & 1u)) >> 16;
  unsigned rb = (cb.u + 0x7fffu + ((cb.u >> 16) & 1u)) >> 16;
  return ra | (rb << 16);
}
__device__ __forceinline__ float bflo_(unsigned u) { return __uint_as_float(u << 16); }
__device__ __forceinline__ float bfhi_(unsigned u) { return __uint_as_float(u & 0xffff0000u); }

// 4-row softmax+PV step per kv component (R6/R8/R9 proven)
#define MHA_STEP(K0C, K1C, V0C, V1C)                         \
  {                                                          \
    _Pragma("unroll") for (int i = 0; i < 4; ++i) {          \
      float s = fmaf(q0[i], K0C, q1[i] * K1C);               \
      float p = exp2_(s);                                    \
      ps[i] += p;                                            \
      c0[i] = fmaf(p, V0C, c0[i]);                           \
      c1[i] = fmaf(p, V1C, c1[i]);                           \
    }                                                        \
  }

// ---------------- K1: input_proj + GRU + MHA, one block per (b, 8f) ----------------
// grid: B*(F/8) = 512 blocks, 256 threads = 4 waves.
__global__ __launch_bounds__(256, 2) void k_fused(
    const float* __restrict__ x, const float* __restrict__ Wp, const float* __restrict__ bp,
    const float* __restrict__ W_ih, const float* __restrict__ b_ih,
    const float* __restrict__ W_hh, const float* __restrict__ b_hh,
    const float* __restrict__ in_w, const float* __restrict__ in_b,
    const float* __restrict__ ow, const float* __restrict__ ob,
    ushort* __restrict__ outp, float* __restrict__ attn) {
  __shared__ float smem[SM_SIZE];
  const int tid = threadIdx.x;
  const int blk = blockIdx.x;
  const int b = blk >> 4;
  const int f0 = (blk & 15) * 8;
  const int lane = tid & 63;
  const int w = tid >> 6;

  // ---- phase A: stage x[b] (64x128); compute xp for this block's 8 f's ----
  {
    const float2* xb = (const float2*)(x + b * Tt * Ff);
    for (int i = tid; i < Tt * Ff / 2; i += 256) {
      int row = i >> 6, col2 = i & 63;
      *(float2*)&smem[row * XS_STRIDE + col2 * 2] = xb[i];
    }
  }
  __syncthreads();
  {
    const int t = lane;
    const int fA = f0 + w, fB = f0 + w + 4;  // wave-uniform -> scalar Wp loads
    float acc0 = bp[fA], acc1 = bp[fB];
    const float* wA = Wp + fA * Ff;
    const float* wB = Wp + fB * Ff;
    const float* xr = &smem[t * XS_STRIDE];
#pragma unroll 8
    for (int k = 0; k < Ff; k += 2) {
      float2 xv = *(const float2*)&xr[k];
      acc0 = fmaf(xv.x, wA[k], acc0); acc0 = fmaf(xv.y, wA[k + 1], acc0);
      acc1 = fmaf(xv.x, wB[k], acc1); acc1 = fmaf(xv.y, wB[k + 1], acc1);
    }
    smem[XP + w * 65 + t] = acc0;
    smem[XP + (w + 4) * 65 + t] = acc1;
  }
  __syncthreads();   // xp ready; xs region dead -> hout overlays it

  // ---- phase B: GRU scan over T, wave 0 only; h -> LDS ----
  if (tid < 64) {
    __builtin_amdgcn_s_setprio(1);
    const int g = tid >> 3, j = tid & 7;
    const int f = f0 + g;
    const float* wb = W_hh + (f * G3H + j) * Hh;
    const float nL = -L2E, S2 = 2.0f * L2E;
    float w0s[8], w1s[8], w2s[8];
#pragma unroll
    for (int h = 0; h < 8; ++h) {
      w0s[h] = wb[h] * nL;
      w1s[h] = wb[64 + h] * nL;
      w2s[h] = wb[128 + h] * S2;
    }
    const float wi0s = W_ih[f * G3H + j] * nL;
    const float wi1s = W_ih[f * G3H + 8 + j] * nL;
    const float wi2s = W_ih[f * G3H + 16 + j] * S2;
    const float bias_r = (b_ih[f * G3H + j] + b_hh[f * G3H + j]) * nL;
    const float bias_z = (b_ih[f * G3H + 8 + j] + b_hh[f * G3H + 8 + j]) * nL;
    const float bi2s = b_ih[f * G3H + 16 + j] * S2;
    const float bh2s = b_hh[f * G3H + 16 + j] * S2;
    float hall[8];
#pragma unroll
    for (int h = 0; h < 8; ++h) hall[h] = 0.f;
    float h_own = 0.f;
    const int base = tid & 56;
    float* hdst = &smem[g * 520 + j * 65];   // hout[g][j][t]
    const float* xps = &smem[XP + g * 65];
    for (int t = 0; t < Tt; ++t) {
      float xt = xps[t];
      float a0 = bias_r, a1 = bias_z, a2 = bh2s;
#pragma unroll
      for (int h = 0; h < 8; ++h) {
        a0 = fmaf(hall[h], w0s[h], a0);
        a1 = fmaf(hall[h], w1s[h], a1);
        a2 = fmaf(hall[h], w2s[h], a2);
      }
      float r = rcp_(1.0f + exp2_(fmaf(xt, wi0s, a0)));
      float z = rcp_(1.0f + exp2_(fmaf(xt, wi1s, a1)));
      float narg = fmaf(r, a2, fmaf(xt, wi2s, bi2s));
      float n = fmaf(-2.0f, rcp_(exp2_(narg) + 1.0f), 1.0f);  // tanh
      float hn = fmaf(z, h_own - n, n);
      hdst[t] = hn;
      h_own = hn;
#pragma unroll
      for (int h = 0; h < 8; ++h) hall[h] = __shfl(hn, base + h, 64);
    }
    __builtin_amdgcn_s_setprio(0);
  }
  __syncthreads();   // hout ready for all waves

  // ---- burst-write h tile to global as bf16: 8f x 64t rows of 8 bf16 (16B each) ----
  {
    ushort* og = outp + (size_t)(b * Ff + f0) * Tt * Hh;
#pragma unroll
    for (int i = 0; i < 2; ++i) {
      int v = i * 256 + tid;               // row index (512 total)
      int fl = v >> 6, tt = v & 63;
      const float* hp = &smem[fl * 520 + tt];
      unsigned d0 = bfp_(hp[0],   hp[65]);
      unsigned d1 = bfp_(hp[130], hp[195]);
      unsigned d2 = bfp_(hp[260], hp[325]);
      unsigned d3 = bfp_(hp[390], hp[455]);
      *(uint4*)(og + (size_t)v * 8) = make_uint4(d0, d1, d2, d3);
    }
  }

  // ---- phase C: MHA; wave w handles f_local = w and w+4, fully wave-private ----
  {
    const int t = lane;
    float* sm = &smem[WKV + w * 1728];
    constexpr float SCL = 0.70710678118654752f * L2E;
#pragma unroll
    for (int fl = w; fl < 8; fl += 4) {
      const float* hsrc = &smem[fl * 520];
      // C1: qkv projection from LDS-resident f32 h
      float sq[8];
#pragma unroll
      for (int h = 0; h < 8; ++h) sq[h] = hsrc[h * 65 + t];
      float qv[8], ka[8], va[8];
#pragma unroll
      for (int jj = 0; jj < 8; ++jj) {
        float aq = in_b[jj], ak = in_b[8 + jj], av = in_b[16 + jj];
#pragma unroll
        for (int h = 0; h < 8; ++h) {
          aq = fmaf(sq[h], in_w[jj * 8 + h], aq);
          ak = fmaf(sq[h], in_w[(8 + jj) * 8 + h], ak);
          av = fmaf(sq[h], in_w[(16 + jj) * 8 + h], av);
        }
        qv[jj] = aq * SCL; ka[jj] = ak; va[jj] = av;
      }
#pragma unroll
      for (int n = 0; n < 4; ++n) {
        *(float2*)&sm[QS + t * 10 + 2 * n] = make_float2(qv[2 * n], qv[2 * n + 1]);
        sm[KK0 + n * 68 + t] = ka[2 * n];
        sm[KK1 + n * 68 + t] = ka[2 * n + 1];
        sm[VV0 + n * 68 + t] = va[2 * n];
        sm[VV1 + n * 68 + t] = va[2 * n + 1];
      }
      asm volatile("s_waitcnt lgkmcnt(0)" ::: "memory");  // within-wave RAW

      // C2: lane = (n = t>>4, qq = t&15); 4 q-rows x 1 head
      const int n = t >> 4, qq = t & 15;
      float q0[4], q1[4];
#pragma unroll
      for (int i = 0; i < 4; ++i) {
        float2 qp = *(const float2*)&sm[QS + (qq + 16 * i) * 10 + 2 * n];
        q0[i] = qp.x; q1[i] = qp.y;
      }
      float ps[4], c0[4], c1[4];
#pragma unroll
      for (int i = 0; i < 4; ++i) { ps[i] = 0.f; c0[i] = 0.f; c1[i] = 0.f; }
#pragma unroll 2
      for (int kt4 = 0; kt4 < Tt; kt4 += 4) {
        float4 k0 = *(const float4*)&sm[KK0 + n * 68 + kt4];
        float4 k1 = *(const float4*)&sm[KK1 + n * 68 + kt4];
        float4 v0 = *(const float4*)&sm[VV0 + n * 68 + kt4];
        float4 v1 = *(const float4*)&sm[VV1 + n * 68 + kt4];
        MHA_STEP(k0.x, k1.x, v0.x, v1.x)
        MHA_STEP(k0.y, k1.y, v0.y, v1.y)
        MHA_STEP(k0.z, k1.z, v0.z, v1.z)
        MHA_STEP(k0.w, k1.w, v0.w, v1.w)
      }
#pragma unroll
      for (int i = 0; i < 4; ++i) {
        float inv = rcp_(ps[i]);
        *(float2*)&sm[QS + (qq + 16 * i) * 10 + 2 * n] =
            make_float2(c0[i] * inv, c1[i] * inv);   // ctx over q
      }
      asm volatile("s_waitcnt lgkmcnt(0)" ::: "memory");

      // C3: out_proj of ctx row t -> stage in OCT
      {
        float2 cp0 = *(const float2*)&sm[QS + t * 10 + 0];
        float2 cp1 = *(const float2*)&sm[QS + t * 10 + 2];
        float2 cp2 = *(const float2*)&sm[QS + t * 10 + 4];
        float2 cp3 = *(const float2*)&sm[QS + t * 10 + 6];
        float cx[8] = {cp0.x, cp0.y, cp1.x, cp1.y, cp2.x, cp2.y, cp3.x, cp3.y};
        float o8[8];
#pragma unroll
        for (int jj = 0; jj < 8; ++jj) {
          float a = ob[jj];
#pragma unroll
          for (int h = 0; h < 8; ++h) a = fmaf(cx[h], ow[jj * 8 + h], a);
          o8[jj] = a;
        }
        float* od = &smem[OCT + fl * 640 + t * 10];
        *(float4*)&od[0] = make_float4(o8[0], o8[1], o8[2], o8[3]);
        *(float4*)&od[4] = make_float4(o8[4], o8[5], o8[6], o8[7]);
      }
    }
  }
  __syncthreads();

  // ---- burst attn store: per t, 8f x 8h = 256B contiguous ----
  {
#pragma unroll
    for (int i = 0; i < 4; ++i) {
      int v = i * 256 + tid;            // float4 index (1024 total)
      int t = v >> 4;
      int c = v & 15;                   // f = c>>1, h0 = (c&1)*4
      const float* sp = &smem[OCT + (c >> 1) * 640 + t * 10 + (c & 1) * 4];
      float4* dst = (float4*)(attn + ((b * Tt + t) * Ff + f0) * Hh);
      dst[c] = *(const float4*)sp;
    }
  }
}

// ---------------- K2: y = out.reshape(B,T,F*H) @ Wout^T + bout (bf16 reads) ----------------
// grid: B*(T/8) = 256 blocks, 128 threads = 8 o-quads x 16 f-chunks.
__global__ __launch_bounds__(128) void k_outproj(
    const ushort* __restrict__ outp, const float* __restrict__ Wout,
    const float* __restrict__ bout, float* __restrict__ y) {
  constexpr int TT = 8;
  int blk = blockIdx.x;
  int b = blk >> 3;
  int t0 = (blk & 7) * TT;
  int tid = threadIdx.x;
  int oq = tid >> 4;
  int fc = tid & 15;
  float acc[TT][4];
#pragma unroll
  for (int tt = 0; tt < TT; ++tt)
#pragma unroll
    for (int od = 0; od < 4; ++od) acc[tt][od] = 0.f;
#pragma unroll
  for (int ff = 0; ff < 8; ++ff) {
    int f = fc * 8 + ff;
    const uint4* rb = (const uint4*)(outp + (size_t)((b * Ff + f) * Tt + t0) * Hh);
    uint4 rq[TT];
#pragma unroll
    for (int i = 0; i < TT; ++i) rq[i] = rb[i];   // one uint4 = one t row (8 bf16)
    float4 rv[16];
#pragma unroll
    for (int tt = 0; tt < TT; ++tt) {
      uint4 q = rq[tt];
      rv[tt * 2]     = make_float4(bflo_(q.x), bfhi_(q.x), bflo_(q.y), bfhi_(q.y));
      rv[tt * 2 + 1] = make_float4(bflo_(q.z), bfhi_(q.z), bflo_(q.w), bfhi_(q.w));
    }
#pragma unroll
    for (int od = 0; od < 4; ++od) {
      int o = oq * 4 + od;
      const float4* wbp = (const float4*)(Wout + o * (Ff * Hh) + f * Hh);
      float4 wa = wbp[0], wc = wbp[1];
#pragma unroll
      for (int tt = 0; tt < TT; ++tt) {
        float4 ra = rv[tt * 2], rc = rv[tt * 2 + 1];
        float s = acc[tt][od];
        s = fmaf(ra.x, wa.x, s); s = fmaf(ra.y, wa.y, s);
        s = fmaf(ra.z, wa.z, s); s = fmaf(ra.w, wa.w, s);
        s = fmaf(rc.x, wc.x, s); s = fmaf(rc.y, wc.y, s);
        s = fmaf(rc.z, wc.z, s); s = fmaf(rc.w, wc.w, s);
        acc[tt][od] = s;
      }
    }
  }
#pragma unroll
  for (int tt = 0; tt < TT; ++tt)
#pragma unroll
    for (int od = 0; od < 4; ++od) {
      float v = acc[tt][od];
      v += __shfl_xor(v, 1, 16);
      v += __shfl_xor(v, 2, 16);
      v += __shfl_xor(v, 4, 16);
      v += __shfl_xor(v, 8, 16);
      acc[tt][od] = v;
    }
#pragma unroll
  for (int tt = 0; tt < TT; ++tt) {
    if (fc == tt) {
#pragma unroll
      for (int od = 0; od < 4; ++od) {
        int o = oq * 4 + od;
        y[(b * Tt + t0 + tt) * HIDh + o] = acc[tt][od] + bout[o];
      }
    }
  }
}

extern "C" void kernel_launch(void* const* d_in, const int* in_sizes, int n_in,
                              void* d_out, int out_size, void* d_ws, size_t ws_size,
                              hipStream_t stream) {
  (void)in_sizes; (void)n_in; (void)out_size; (void)ws_size;
  const float* x    = (const float*)d_in[0];
  const float* Wp   = (const float*)d_in[1];
  const float* bp   = (const float*)d_in[2];
  const float* W_ih = (const float*)d_in[3];
  const float* b_ih = (const float*)d_in[4];
  const float* W_hh = (const float*)d_in[5];
  const float* b_hh = (const float*)d_in[6];
  const float* in_w = (const float*)d_in[7];
  const float* in_b = (const float*)d_in[8];
  const float* ow   = (const float*)d_in[9];
  const float* ob   = (const float*)d_in[10];
  const float* Wout = (const float*)d_in[11];
  const float* bout = (const float*)d_in[12];

  float* y     = (float*)d_out;
  float* attn  = (float*)d_out + Bb * Tt * HIDh;
  ushort* outp = (ushort*)d_ws;   // B*F*T*H bf16 (4 MB)

  hipLaunchKernelGGL(k_fused, dim3(Bb * (Ff / 8)), dim3(256), 0, stream,
                     x, Wp, bp, W_ih, b_ih, W_hh, b_hh, in_w, in_b, ow, ob, outp, attn);
  hipLaunchKernelGGL(k_outproj, dim3(Bb * (Tt / 8)), dim3(128), 0, stream,
                     outp, Wout, bout, y);
}